// Round 3
// baseline (275.069 us; speedup 1.0000x reference)
//
#include <hip/hip_runtime.h>
#include <hip/hip_bf16.h>

#define B_    16
#define M_    4096
#define K_    512
#define O_    512

#define BM 64
#define NT 16   // K-tiles of 32

typedef float f32x4 __attribute__((ext_vector_type(4)));
typedef short bf16x8 __attribute__((ext_vector_type(8)));
typedef unsigned short u16x8 __attribute__((ext_vector_type(8)));

// ---------------- kernel 1: s[b,i] = sum_f w[b,f]*A_w[i,f] + A_b[i] ----------------
__global__ void style_kernel(const float* __restrict__ w, const float* __restrict__ A_w,
                             const float* __restrict__ A_b, float* __restrict__ s) {
    __shared__ float wsh[16][516];
    __shared__ float ash[16][516];
    int t = threadIdx.x;
    for (int idx = t; idx < 2048; idx += 256) {
        int row = idx >> 7, q = (idx & 127) * 4;
        *(float4*)&wsh[row][q] = *(const float4*)&w[row * 512 + q];
    }
    int i0 = blockIdx.x * 16;
    for (int idx = t; idx < 2048; idx += 256) {
        int row = idx >> 7, q = (idx & 127) * 4;
        *(float4*)&ash[row][q] = *(const float4*)&A_w[(size_t)(i0 + row) * 512 + q];
    }
    __syncthreads();
    int b = t >> 4, il = t & 15;
    float acc = 0.f;
    #pragma unroll 8
    for (int f = 0; f < 512; f += 4) {
        float4 wa = *(const float4*)&wsh[b][f];
        float4 aa = *(const float4*)&ash[il][f];
        acc += wa.x * aa.x + wa.y * aa.y + wa.z * aa.z + wa.w * aa.w;
    }
    s[b * 512 + i0 + il] = acc + A_b[i0 + il];
}

// ---------------- kernel 2: demodulate -> bf16, FRAGMENT-TILED layout ----------------
// wd2 element (b, o, k), k = ks*32 + kq*8 + j lives at
//   ((((b*16 + ks)*32 + (o>>4))*4 + kq)*16 + (o&15))*8 + j
// so a GEMM B-fragment (b, ks, colgroup) is 1 KB contiguous, lane l at byte l*16.
__global__ void demod_kernel(const float* __restrict__ weight, const float* __restrict__ s,
                             unsigned short* __restrict__ wd2) {
    int gw = blockIdx.x * 4 + (threadIdx.x >> 6);
    int lane = threadIdx.x & 63;
    int b = gw >> 9;
    int o = gw & 511;
    const float* wrow = weight + (size_t)o * 512;
    const float* srow = s + b * 512;
    int k0 = lane * 8;
    f32x4 w0 = *(const f32x4*)(wrow + k0);
    f32x4 w1 = *(const f32x4*)(wrow + k0 + 4);
    f32x4 s0 = *(const f32x4*)(srow + k0);
    f32x4 s1 = *(const f32x4*)(srow + k0 + 4);
    float vals[8];
    float ss = 0.f;
    #pragma unroll
    for (int j = 0; j < 4; j++) { float v = w0[j] * s0[j]; vals[j] = v; ss += v * v; }
    #pragma unroll
    for (int j = 0; j < 4; j++) { float v = w1[j] * s1[j]; vals[4 + j] = v; ss += v * v; }
    #pragma unroll
    for (int off = 32; off; off >>= 1) ss += __shfl_xor(ss, off);
    float nrm = rsqrtf(1e-8f + ss);
    int ks = lane >> 2, kq = lane & 3;
    size_t base = (((((size_t)b * 16 + ks) * 32 + (o >> 4)) * 4 + kq) * 16 + (o & 15)) * 8;
    u16x8 pack;
    #pragma unroll
    for (int j = 0; j < 8; j++) {
        unsigned int u = __builtin_bit_cast(unsigned int, vals[j] * nrm);
        u += 0x7fffu + ((u >> 16) & 1u);
        pack[j] = (unsigned short)(u >> 16);
    }
    *(u16x8*)(wd2 + base) = pack;
}

// ---------------- kernel 3: out[b,n,o] = relu( x[b]·wd[b]^T + bias ) ----------------
// v4: same geometry as v3 (BM=64 x BN=512, x-panel resident in LDS, no main-loop
// barriers), but the B stream is pipelined as a RING of 4 batches x 4 fragments
// with prefetch distance 3 — steady-state ~12 KB in flight per wave (3x v3) to
// attack the Little's-law MLP ceiling. A-fragments double-buffered (distance 1).
// All ring indices compile-time (full unroll).
__global__ __launch_bounds__(256, 2) void gemm_kernel(const float* __restrict__ x,
                                                      const unsigned short* __restrict__ wd2,
                                                      const float* __restrict__ bias,
                                                      float* __restrict__ out) {
    __shared__ unsigned short sA[BM * 64 * 8];   // 64 rows x 64 chunks x 16 B = 64 KB

    // XCD swizzle: XCD owns 2 consecutive b values (1 MB wd2 L2-resident).
    int g = blockIdx.x;
    int xcd = g & 7;
    int r = g >> 3;                  // [0,128)
    const int b  = xcd * 2 + (r >> 6);
    const int m0 = (r & 63) * BM;

    const int t = threadIdx.x;
    const int w = t >> 6;
    const int l = t & 63;

    // ---- prologue: stage x panel (64x512 fp32 -> bf16 LDS), one barrier ----
    const float* xb = x + ((size_t)b * M_ + m0) * K_;
    #pragma unroll
    for (int rr = 0; rr < 16; rr++) {
        int row = rr * 4 + w;                       // wave-uniform row
        const float* src = xb + (size_t)row * K_ + l * 8;
        f32x4 u = *(const f32x4*)src;
        f32x4 v = *(const f32x4*)(src + 4);
        union { __hip_bfloat162 h[4]; u16x8 vv; } cv;
        cv.h[0] = __float22bfloat162_rn(float2{u[0], u[1]});
        cv.h[1] = __float22bfloat162_rn(float2{u[2], u[3]});
        cv.h[2] = __float22bfloat162_rn(float2{v[0], v[1]});
        cv.h[3] = __float22bfloat162_rn(float2{v[2], v[3]});
        int chunk = row * 64 + (l & ~7) + ((l ^ row) & 7);
        *(u16x8*)(&sA[chunk * 8]) = cv.vv;
    }
    __syncthreads();   // the ONLY barrier in this kernel

    // B fragment base: frag(ks, ni) at wb + (ks*32 + ni)*512 elems, lane offset l*8
    const unsigned short* wb = wd2 + (size_t)b * 262144 + (size_t)(w * 8) * 512 + (size_t)l * 8;

    const int rowl = l & 15;
    const int kqv  = l >> 4;

    f32x4 acc[4][8] = {};
    bf16x8 bfr[4][4];   // ring: batch h covers ks=h>>1, ni-half h&1
    bf16x8 af[2][4];    // A-fragment double buffer

#define LOAD_B(h)                                                                        \
    _Pragma("unroll")                                                                    \
    for (int ni = 0; ni < 4; ni++)                                                       \
        bfr[(h) & 3][ni] =                                                               \
            *(const bf16x8*)(wb + ((size_t)((h) >> 1) * 32 + ((h) & 1) * 4 + ni) * 512);

#define LOAD_A(ks)                                                                       \
    _Pragma("unroll")                                                                    \
    for (int mi = 0; mi < 4; mi++) {                                                     \
        int row = mi * 16 + rowl;                                                        \
        int c = (ks) * 4 + kqv;                                                          \
        int chunk = row * 64 + (c & ~7) + ((c ^ row) & 7);                               \
        af[(ks) & 1][mi] = *(const bf16x8*)(&sA[chunk * 8]);                             \
    }

    LOAD_B(0); LOAD_B(1); LOAD_B(2);
    LOAD_A(0);

    #pragma unroll
    for (int h = 0; h < 2 * NT; h++) {
        const int ks = h >> 1;
        if (h + 3 < 2 * NT) { LOAD_B(h + 3); }            // keep 3 batches in flight
        if ((h & 1) == 1 && ks + 1 < NT) { LOAD_A(ks + 1); }
        __builtin_amdgcn_s_setprio(1);
        #pragma unroll
        for (int mi = 0; mi < 4; mi++)
            #pragma unroll
            for (int ni = 0; ni < 4; ni++)
                acc[mi][(h & 1) * 4 + ni] = __builtin_amdgcn_mfma_f32_16x16x32_bf16(
                    af[ks & 1][mi], bfr[h & 3][ni], acc[mi][(h & 1) * 4 + ni], 0, 0, 0);
        __builtin_amdgcn_s_setprio(0);
    }
#undef LOAD_B
#undef LOAD_A

    // epilogue: C/D layout col=lane&15, row=(lane>>4)*4+reg  [m89-verified]
    const int col_l = l & 15;
    const int row_q = (l >> 4) * 4;
    #pragma unroll
    for (int ni = 0; ni < 8; ni++) {
        int o = w * 128 + ni * 16 + col_l;
        float bv = bias[o];
        #pragma unroll
        for (int mi = 0; mi < 4; mi++) {
            int mrow = m0 + mi * 16 + row_q;
            #pragma unroll
            for (int rr2 = 0; rr2 < 4; rr2++) {
                float v = acc[mi][ni][rr2] + bv;
                out[((size_t)b * M_ + mrow + rr2) * O_ + o] = v > 0.f ? v : 0.f;
            }
        }
    }
}

extern "C" void kernel_launch(void* const* d_in, const int* in_sizes, int n_in,
                              void* d_out, int out_size, void* d_ws, size_t ws_size,
                              hipStream_t stream) {
    const float* x      = (const float*)d_in[0];
    const float* w      = (const float*)d_in[1];
    const float* weight = (const float*)d_in[2];
    const float* bias   = (const float*)d_in[3];
    const float* A_w    = (const float*)d_in[4];
    const float* A_b    = (const float*)d_in[5];
    float* out = (float*)d_out;

    unsigned short* wd2 = (unsigned short*)d_ws;                             // 8.4 MB tiled
    float* s = (float*)((char*)d_ws + (size_t)B_ * O_ * K_ * sizeof(unsigned short));

    style_kernel<<<32, 256, 0, stream>>>(w, A_w, A_b, s);
    demod_kernel<<<(B_ * O_) / 4, 256, 0, stream>>>(weight, s, wd2);
    gemm_kernel<<<1024, 256, 0, stream>>>(x, wd2, bias, out);
}